// Round 17
// baseline (267.512 us; speedup 1.0000x reference)
//
#include <hip/hip_runtime.h>
#include <hip/hip_fp16.h>
#include <math.h>
#include <complex>

#define NN 100000
#define NE 1600000
#define NG 64
#define NBUCK 782          // ceil(NN/128); bucket = dst >> 7
#define SCB 512
#define SEB 3125           // SCB*SEB == NE
#define TBINS 256          // layers 1,3 table bins
#define TB2   128          // layer 2 table bins (LDS budget)
#define MAXB  2560         // max edges per bucket
#define NBLK_E   6250
#define NBLK_N8  3125
#define NBLK_SCAN 391

// ---------------- CG tables (host) ----------------
struct CGTables {
  float c000;
  float c011[3][3];
  float c101[3][3];
  float c110[3][3];
  float c111[3][3][3];
  float c121[3][3][5];
};
struct CGConsts {
  float c000;
  float l011, l101, l110, l111;
  float s121[5][5];
};

static double hfact(int n){ double r=1.0; for(int i=2;i<=n;++i) r*=(double)i; return r; }

static double host_cgc(int j1,int m1,int j2,int m2,int j3,int m3){
  if (m1+m2 != m3) return 0.0;
  double pre = sqrt((2.0*j3+1.0)*hfact(j3+j1-j2)*hfact(j3-j1+j2)*hfact(j1+j2-j3)/hfact(j1+j2+j3+1));
  pre *= sqrt(hfact(j3+m3)*hfact(j3-m3)*hfact(j1-m1)*hfact(j1+m1)*hfact(j2-m2)*hfact(j2+m2));
  int k0 = 0; if (j2-j3-m1 > k0) k0 = j2-j3-m1; if (j1-j3+m2 > k0) k0 = j1-j3+m2;
  int k1 = j1+j2-j3; if (j1-m1 < k1) k1 = j1-m1; if (j2+m2 < k1) k1 = j2+m2;
  double s = 0.0;
  for (int k=k0;k<=k1;++k){
    double t = 1.0/(hfact(k)*hfact(j1+j2-j3-k)*hfact(j1-m1-k)*hfact(j2+m2-k)*hfact(j3-j2+m1+k)*hfact(j3-j1-m2+k));
    s += (k&1) ? -t : t;
  }
  return pre*s;
}

typedef std::complex<double> cd;

static void host_u(int l, cd U[5][5]){
  for (int a=0;a<5;++a) for (int b=0;b<5;++b) U[a][b] = 0.0;
  U[l][l] = 1.0;
  const double is2 = 1.0/sqrt(2.0);
  for (int m=1;m<=l;++m){
    double sgn = (m&1) ? -1.0 : 1.0;
    U[l+m][l+m] = sgn*is2;
    U[l+m][l-m] = is2;
    U[l-m][l-m] = cd(0.0, is2);
    U[l-m][l+m] = cd(0.0, -sgn*is2);
  }
}

static void host_real_cg(int l1,int l2,int l3, float* out){
  cd U1[5][5], U2[5][5], U3[5][5];
  host_u(l1,U1); host_u(l2,U2); host_u(l3,U3);
  int n1=2*l1+1, n2=2*l2+1, n3=2*l3+1;
  double cgt[5][5][5];
  for (int i=0;i<5;++i) for (int j=0;j<5;++j) for (int k=0;k<5;++k) cgt[i][j][k]=0.0;
  for (int m1=-l1;m1<=l1;++m1) for (int m2=-l2;m2<=l2;++m2){
    int m3 = m1+m2;
    if (m3 >= -l3 && m3 <= l3) cgt[l1+m1][l2+m2][l3+m3] = host_cgc(l1,m1,l2,m2,l3,m3);
  }
  cd W[5][5][5];
  double sre=0.0, sim=0.0;
  for (int c=0;c<n3;++c) for (int a=0;a<n1;++a) for (int b=0;b<n2;++b){
    cd acc = 0.0;
    for (int i=0;i<n1;++i) for (int j=0;j<n2;++j) for (int k=0;k<n3;++k)
      acc += U1[a][i]*U2[b][j]*std::conj(U3[c][k])*cgt[i][j][k];
    W[c][a][b] = acc;
    sre += fabs(acc.real()); sim += fabs(acc.imag());
  }
  bool use_re = (sre >= sim);
  for (int c=0;c<n3;++c) for (int a=0;a<n1;++a) for (int b=0;b<n2;++b)
    out[(c*n1+a)*n2+b] = (float)(use_re ? W[c][a][b].real() : W[c][a][b].imag());
}

static void build_cg_tables(CGTables& t){
  float w000[1];  host_real_cg(0,0,0,w000); t.c000 = w000[0];
  float w011[9];  host_real_cg(0,1,1,w011);
  for (int o=0;o<3;++o) for (int b=0;b<3;++b) t.c011[o][b] = w011[o*3+b];
  float w101[9];  host_real_cg(1,0,1,w101);
  for (int o=0;o<3;++o) for (int a=0;a<3;++a) t.c101[o][a] = w101[o*3+a];
  float w110[9];  host_real_cg(1,1,0,w110);
  for (int a=0;a<3;++a) for (int b=0;b<3;++b) t.c110[a][b] = w110[a*3+b];
  float w111[27]; host_real_cg(1,1,1,w111);
  for (int o=0;o<3;++o) for (int a=0;a<3;++a) for (int b=0;b<3;++b) t.c111[o][a][b] = w111[(o*3+a)*3+b];
  float w121[45]; host_real_cg(1,2,1,w121);
  for (int o=0;o<3;++o) for (int a=0;a<3;++a) for (int b=0;b<5;++b) t.c121[o][a][b] = w121[(o*3+a)*5+b];
}

static void build_cg_consts(const CGTables& t, CGConsts& K){
  K.c000 = t.c000;
  K.l011 = t.c011[0][0];
  K.l101 = t.c101[0][0];
  K.l110 = t.c110[0][0];
  K.l111 = t.c111[0][1][2];
  const int pi[5] = {0,0,0,1,1};
  const int pj[5] = {0,1,2,1,2};
  for (int p=0;p<5;++p)
    for (int b=0;b<5;++b)
      K.s121[p][b] = 0.5f*(t.c121[pi[p]][pj[p]][b] + t.c121[pj[p]][pi[p]][b]);
}

// ---------------- device helpers ----------------
__device__ __forceinline__ float sspf(float v){
  float sp = (v > 30.0f) ? v : log1pf(expf(v));
  return sp - 0.69314718055994531f;
}

__device__ __forceinline__ float cutoff_w(float len){
  float u = len * (1.0f/1.5f);
  float u2 = u*u, u6 = u2*u2*u2, u7 = u6*u, u8 = u7*u;
  float cut = 1.0f - 28.0f*u6 + 48.0f*u7 - 21.0f*u8;
  return (u < 1.0f) ? cut : 0.0f;
}

__device__ __forceinline__ float pack2h(float a, float b){
  __half2 h = __floats2half2_rn(a, b);
  return *reinterpret_cast<float*>(&h);
}
__device__ __forceinline__ float2 unpack2h(float f){
  __half2 h = *reinterpret_cast<__half2*>(&f);
  return __half22float2(h);
}

// ================= radial-weight table build =================
__global__ __launch_bounds__(256) void lwtab_kernel(
    const float* __restrict__ wpw, const float* __restrict__ wpb,
    int NP, int bins, float* __restrict__ tab)
{
  int idx = blockIdx.x*256 + threadIdx.x;
  int tot = bins*NP*8;
  if (idx >= tot) return;
  int stride = NP*8;
  int bin = idx / stride;
  int r = idx - bin*stride;
  float len = (1.5f/(bins-1)) * bin;
  float v = wpb[r];
  #pragma unroll
  for (int i=0;i<10;++i){
    float dd = len - (0.7f + (float)i*(1.0f/9.0f));
    v = fmaf(wpw[i*stride + r], __expf(-50.0f*dd*dd), v);
  }
  tab[idx] = v;
}

// ================= bucket hist / scan =================
__global__ __launch_bounds__(1024) void bhist_kernel(const int* __restrict__ dst, int* __restrict__ bcnt){
  __shared__ int cnt[NBUCK];
  for (int j=threadIdx.x; j<NBUCK; j+=1024) cnt[j] = 0;
  __syncthreads();
  int base = blockIdx.x * SEB;
  for (int i=threadIdx.x; i<SEB; i+=1024)
    atomicAdd(&cnt[dst[base+i] >> 7], 1);
  __syncthreads();
  for (int j=threadIdx.x; j<NBUCK; j+=1024)
    if (cnt[j]) atomicAdd(&bcnt[j], cnt[j]);
}

__global__ __launch_bounds__(1024) void bscan_kernel(const int* __restrict__ bcnt,
                                                     int* __restrict__ bbase, int* __restrict__ bclaim){
  __shared__ int s[1024];
  int t = threadIdx.x;
  int v = (t < NBUCK) ? bcnt[t] : 0;
  s[t] = v; __syncthreads();
  for (int off=1; off<1024; off<<=1){
    int u = (t >= off) ? s[t-off] : 0;
    __syncthreads();
    s[t] += u;
    __syncthreads();
  }
  if (t < NBUCK){
    int excl = s[t] - v;
    bbase[t] = excl;
    bclaim[t] = excl;
    if (t == NBUCK-1) bbase[NBUCK] = excl + v;
  }
}

// ================= bucketed record scatter (256 threads, 512 windows) =================
// 32B record:
//  q0 = (sn | dl<<20, len, h2(wsh0,wshx), h2(wshy,wshz))
//  q1 = (h2(S00,S01), h2(S02,S11), S12, x0)
__global__ __launch_bounds__(256) void scatter_rec_kernel(
    const int* __restrict__ src, const int* __restrict__ dst,
    const float* __restrict__ sh, const float* __restrict__ elen,
    const float* __restrict__ x,
    int* __restrict__ bclaim, float4* __restrict__ rec, CGConsts K)
{
  __shared__ int cnt[NBUCK];
  __shared__ int bs[NBUCK];
  for (int j=threadIdx.x; j<NBUCK; j+=256) cnt[j] = 0;
  __syncthreads();
  int base = blockIdx.x * SEB;
  for (int i=threadIdx.x; i<SEB; i+=256)
    atomicAdd(&cnt[dst[base+i] >> 7], 1);
  __syncthreads();
  for (int j=threadIdx.x; j<NBUCK; j+=256){
    int c = cnt[j];
    if (c) bs[j] = atomicAdd(&bclaim[j], c);
    cnt[j] = 0;
  }
  __syncthreads();
  for (int i=threadIdx.x; i<SEB; i+=256){
    int e = base + i;
    int d = dst[e];
    int b = d >> 7;
    int off = atomicAdd(&cnt[b], 1);
    int slot = bs[b] + off;
    float len = elen[e];
    float w = cutoff_w(len);
    const float* shr = sh + (size_t)e*9;
    float sh0 = shr[0]*w, shx = shr[1]*w, shy = shr[2]*w, shz = shr[3]*w;
    float b0 = shr[4], b1 = shr[5], b2 = shr[6], b3 = shr[7], b4 = shr[8];
    float S[5];
    #pragma unroll
    for (int p=0;p<5;++p)
      S[p] = (K.s121[p][0]*b0 + K.s121[p][1]*b1 + K.s121[p][2]*b2 + K.s121[p][3]*b3 + K.s121[p][4]*b4)*w;
    int sn = src[e];
    float x0 = x[sn];
    int packed = sn | ((d & 127) << 20);
    float4* rp = rec + (size_t)slot*2;
    rp[0] = make_float4(__int_as_float(packed), len, pack2h(sh0, shx), pack2h(shy, shz));
    rp[1] = make_float4(pack2h(S[0], S[1]), pack2h(S[2], S[3]), S[4], x0);
  }
}

// ================= per-bucket sort-copy (L2-hot window) + rowptr =================
__global__ __launch_bounds__(512) void sortcopy_kernel(
    const float4* __restrict__ recin, const int* __restrict__ bbase,
    float4* __restrict__ recout, int* __restrict__ rowptr)
{
  __shared__ int hist[128], offs[128], cur[128];
  __shared__ short outmap[MAXB];
  int b = blockIdx.x;
  int e0 = bbase[b], e1 = bbase[b+1];
  int cnt = e1 - e0;
  int t = threadIdx.x;
  if (t < 128) hist[t] = 0;
  __syncthreads();
  for (int i=t; i<cnt; i+=512){
    int packed = __float_as_int(recin[(size_t)(e0+i)*2].x);
    atomicAdd(&hist[packed >> 20], 1);
  }
  __syncthreads();
  if (t < 128) offs[t] = hist[t];
  __syncthreads();
  for (int off=1; off<128; off<<=1){
    int v = (t < 128 && t >= off) ? offs[t-off] : 0;
    __syncthreads();
    if (t < 128) offs[t] += v;
    __syncthreads();
  }
  int n0 = b << 7;
  int nn = NN - n0; if (nn > 128) nn = 128;
  if (t < 128){
    int excl = offs[t] - hist[t];
    cur[t] = excl;
    if (t < nn) rowptr[n0+t] = e0 + excl;
  }
  if (b == NBUCK-1 && t == 0) rowptr[NN] = NE;
  __syncthreads();
  for (int i=t; i<cnt; i+=512){
    int packed = __float_as_int(recin[(size_t)(e0+i)*2].x);
    int r = atomicAdd(&cur[packed >> 20], 1);
    outmap[r] = (short)i;
  }
  __syncthreads();
  for (int o=t; o<cnt; o+=512){
    int j = outmap[o];
    const float4* rin = recin + (size_t)(e0+j)*2;
    float4* rout = recout + (size_t)(e0+o)*2;
    float4 a = rin[0], bq = rin[1];
    rout[0] = a; rout[1] = bq;
  }
}

// ================= degree binning =================
__global__ __launch_bounds__(256) void deg_hist_kernel(const int* __restrict__ rowptr, int* __restrict__ dcnt){
  __shared__ int lb[256];
  lb[threadIdx.x] = 0; __syncthreads();
  int n = blockIdx.x*256 + threadIdx.x;
  if (n < NN){
    int d = rowptr[n+1]-rowptr[n]; if (d > 255) d = 255;
    atomicAdd(&lb[d], 1);
  }
  __syncthreads();
  if (lb[threadIdx.x]) atomicAdd(&dcnt[threadIdx.x], lb[threadIdx.x]);
}

__global__ void deg_scan_kernel(const int* __restrict__ dcnt, int* __restrict__ dcur){
  __shared__ int s[256];
  int t = threadIdx.x;
  int v = dcnt[t];
  s[t] = v; __syncthreads();
  for (int off=1; off<256; off<<=1){
    int u = (t >= off) ? s[t-off] : 0;
    __syncthreads();
    s[t] += u;
    __syncthreads();
  }
  dcur[t] = s[t] - v;
}

__global__ __launch_bounds__(256) void deg_scatter_kernel(const int* __restrict__ rowptr,
                                                          int* __restrict__ dcur, int* __restrict__ perm){
  __shared__ int lcnt[256];
  __shared__ int lbase[256];
  int t = threadIdx.x;
  lcnt[t] = 0;
  __syncthreads();
  int n = blockIdx.x*256 + t;
  int d = 0, lrank = 0;
  bool valid = (n < NN);
  if (valid){
    d = rowptr[n+1]-rowptr[n]; if (d > 255) d = 255;
    lrank = atomicAdd(&lcnt[d], 1);
  }
  __syncthreads();
  int cnt = lcnt[t];
  if (cnt > 0) lbase[t] = atomicAdd(&dcur[t], cnt);
  __syncthreads();
  if (valid) perm[lbase[d] + lrank] = n;
}

// ================= gather layer 1 =================
__global__ __launch_bounds__(256) void gather1_kernel(
    const int* __restrict__ rowptr, const int* __restrict__ perm,
    const float4* __restrict__ rec, const float* __restrict__ tab,
    const float* __restrict__ si, float* __restrict__ out, CGConsts K)
{
  __shared__ float lwt[TBINS*16];
  for (int i=threadIdx.x; i<TBINS*16; i+=256) lwt[i] = tab[i];
  __syncthreads();
  int gid = blockIdx.x*256 + threadIdx.x;
  int c = gid & 7;
  int n = perm[gid >> 3];
  int r0 = rowptr[n], r1 = rowptr[n+1];
  float a0=0.f, a1=0.f, a2=0.f, a3=0.f;
  #pragma unroll 2
  for (int s=r0; s<r1; ++s){
    const float4* rp = rec + (size_t)s*2;
    float4 q0 = rp[0];
    float4 q1 = rp[1];
    float len = q0.y;
    float2 s01 = unpack2h(q0.z);
    float2 s23 = unpack2h(q0.w);
    float sh0 = s01.x, shx = s01.y, shy = s23.x, shz = s23.y;
    float x0 = q1.w;
    float fb = len * ((TBINS-1)/1.5f);
    int bin = (int)fb; if (bin > TBINS-2) bin = TBINS-2;
    float fr = fb - (float)bin;
    int tb = bin*16 + c;
    float lw0 = fmaf(fr, lwt[tb+16]-lwt[tb], lwt[tb]);
    float lw1 = fmaf(fr, lwt[tb+24]-lwt[tb+8], lwt[tb+8]);
    a0 = fmaf(K.c000*sh0, x0*lw0, a0);
    float t = K.l011*x0*lw1;
    a1 = fmaf(t, shx, a1); a2 = fmaf(t, shy, a2); a3 = fmaf(t, shz, a3);
  }
  float z0=0.f, z1=0.f, z2=0.f, z3=0.f;
  #pragma unroll
  for (int k=0;k<8;++k){
    float y0 = __shfl(a0,k,8), y1 = __shfl(a1,k,8), y2 = __shfl(a2,k,8), y3 = __shfl(a3,k,8);
    float w0 = si[k*8+c], w1 = si[64+k*8+c];
    z0 = fmaf(y0,w0,z0); z1 = fmaf(y1,w1,z1); z2 = fmaf(y2,w1,z2); z3 = fmaf(y3,w1,z3);
  }
  float n0 = sqrtf(z0*z0 + 1e-12f);
  float r0v = z0*(sspf(n0)/n0);
  float nv = sqrtf(z1*z1 + z2*z2 + z3*z3 + 1e-12f);
  float sc = sspf(nv)/nv;
  float4 o = make_float4(r0v, z1*sc, z2*sc, z3*sc);
  *reinterpret_cast<float4*>(out + ((size_t)n*8 + c)*4) = o;   // layout [n][c][m]
}

// ================= gather layer 2 (TB2-bin table) =================
__global__ __launch_bounds__(256) void gather2_kernel(
    const float* __restrict__ hin,           // [NN][8][4]
    const int* __restrict__ rowptr, const int* __restrict__ perm,
    const float4* __restrict__ rec, const float* __restrict__ tab,
    const float* __restrict__ si, float* __restrict__ out, CGConsts K)
{
  __shared__ float lwt[TB2*48];
  for (int i=threadIdx.x; i<TB2*48; i+=256) lwt[i] = tab[i];
  __syncthreads();
  int gid = blockIdx.x*256 + threadIdx.x;
  int c = gid & 7;
  int n = perm[gid >> 3];
  int r0 = rowptr[n], r1 = rowptr[n+1];
  float a0=0.f, a1=0.f, a2=0.f, a3=0.f;
  #pragma unroll 2
  for (int s=r0; s<r1; ++s){
    const float4* rp = rec + (size_t)s*2;
    float4 q0 = rp[0];
    float4 q1 = rp[1];
    int sn = __float_as_int(q0.x) & 0xFFFFF;
    float len = q0.y;
    float2 s01 = unpack2h(q0.z);
    float2 s23 = unpack2h(q0.w);
    float sh0 = s01.x, shx = s01.y, shy = s23.x, shz = s23.y;
    float2 Sa = unpack2h(q1.x);
    float2 Sb = unpack2h(q1.y);
    float S00 = Sa.x, S01 = Sa.y, S02 = Sb.x, S11 = Sb.y, S12 = q1.z;
    float S22 = -S00 - S11;
    float4 hv = *reinterpret_cast<const float4*>(hin + ((size_t)sn*8 + c)*4);
    float x0 = hv.x, xa0 = hv.y, xa1 = hv.z, xa2 = hv.w;
    float fb = len * ((TB2-1)/1.5f);
    int bin = (int)fb; if (bin > TB2-2) bin = TB2-2;
    float fr = fb - (float)bin;
    int tb = bin*48 + c;
    float lw[6];
    #pragma unroll
    for (int p=0;p<6;++p){
      float t0v = lwt[tb + p*8];
      float t1v = lwt[tb + 48 + p*8];
      lw[p] = fmaf(fr, t1v - t0v, t0v);
    }
    float shdotx = shx*xa0 + shy*xa1 + shz*xa2;
    a0 += K.c000*sh0*x0*lw[0] + K.l110*shdotx*lw[3];
    float t011 = K.l011*x0*lw[1];
    float t101 = K.l101*sh0*lw[2];
    float l4 = K.l111*lw[4];
    float sx0 = S00*xa0 + S01*xa1 + S02*xa2;
    float sx1 = S01*xa0 + S11*xa1 + S12*xa2;
    float sx2 = S02*xa0 + S12*xa1 + S22*xa2;
    a1 += t011*shx + t101*xa0 + l4*(xa1*shz - xa2*shy) + sx0*lw[5];
    a2 += t011*shy + t101*xa1 + l4*(xa2*shx - xa0*shz) + sx1*lw[5];
    a3 += t011*shz + t101*xa2 + l4*(xa0*shy - xa1*shx) + sx2*lw[5];
  }
  float z0=0.f, z1=0.f, z2=0.f, z3=0.f;
  #pragma unroll
  for (int k=0;k<8;++k){
    float y0 = __shfl(a0,k,8), y1 = __shfl(a1,k,8), y2 = __shfl(a2,k,8), y3 = __shfl(a3,k,8);
    float w0 = si[k*8+c], w1 = si[64+k*8+c];
    z0 = fmaf(y0,w0,z0); z1 = fmaf(y1,w1,z1); z2 = fmaf(y2,w1,z2); z3 = fmaf(y3,w1,z3);
  }
  float n0 = sqrtf(z0*z0 + 1e-12f);
  float r0v = z0*(sspf(n0)/n0);
  float nv = sqrtf(z1*z1 + z2*z2 + z3*z3 + 1e-12f);
  float sc = sspf(nv)/nv;
  float4 o = make_float4(r0v, z1*sc, z2*sc, z3*sc);
  *reinterpret_cast<float4*>(out + ((size_t)n*8 + c)*4) = o;
}

// ================= gather layer 3 + pool (reads q0 only) =================
__global__ __launch_bounds__(256) void gather3_kernel(
    const float* __restrict__ hin, const int* __restrict__ rowptr, const int* __restrict__ perm,
    const float4* __restrict__ rec, const float* __restrict__ tab,
    const float* __restrict__ si, const int* __restrict__ batch,
    float* __restrict__ G, CGConsts K)
{
  __shared__ float lwt[TBINS*16];
  __shared__ float lg[512];
  for (int i=threadIdx.x; i<TBINS*16; i+=256) lwt[i] = tab[i];
  lg[threadIdx.x] = 0.f; lg[256+threadIdx.x] = 0.f;
  __syncthreads();
  int gid = blockIdx.x*256 + threadIdx.x;
  int c = gid & 7;
  int n = perm[gid >> 3];
  int r0 = rowptr[n], r1 = rowptr[n+1];
  float acc = 0.f;
  #pragma unroll 2
  for (int s=r0; s<r1; ++s){
    float4 q0 = rec[(size_t)s*2];
    int sn = __float_as_int(q0.x) & 0xFFFFF;
    float len = q0.y;
    float2 s01 = unpack2h(q0.z);
    float2 s23 = unpack2h(q0.w);
    float sh0 = s01.x, shx = s01.y, shy = s23.x, shz = s23.y;
    float4 hv = *reinterpret_cast<const float4*>(hin + ((size_t)sn*8 + c)*4);
    float fb = len * ((TBINS-1)/1.5f);
    int bin = (int)fb; if (bin > TBINS-2) bin = TBINS-2;
    float fr = fb - (float)bin;
    int tb = bin*16 + c;
    float lw0 = fmaf(fr, lwt[tb+16]-lwt[tb], lwt[tb]);
    float lw1 = fmaf(fr, lwt[tb+24]-lwt[tb+8], lwt[tb+8]);
    float shdotx = shx*hv.y + shy*hv.z + shz*hv.w;
    acc += K.c000*sh0*hv.x*lw0 + K.l110*shdotx*lw1;
  }
  float z = 0.f;
  #pragma unroll
  for (int k=0;k<8;++k){
    float y = __shfl(acc,k,8);
    z = fmaf(y, si[k*8+c], z);
  }
  float v = z / (1.0f + expf(-z));   // silu
  atomicAdd(&lg[batch[n]*8 + c], v);
  __syncthreads();
  int t = threadIdx.x;
  float v0 = lg[t];     if (v0 != 0.f) unsafeAtomicAdd(&G[t], v0);
  float v1 = lg[256+t]; if (v1 != 0.f) unsafeAtomicAdd(&G[256+t], v1);
}

// ================= final =================
__global__ void final_kernel(
    const float* __restrict__ g, const float* __restrict__ ow,
    const float* __restrict__ ob, float* __restrict__ out)
{
  int i = threadIdx.x;
  if (i >= NG) return;
  float gv[8];
  #pragma unroll
  for (int c=0;c<8;++c) gv[c] = g[i*8+c];
  float lg[8];
  #pragma unroll
  for (int j=0;j<8;++j){
    float acc = ob[j];
    #pragma unroll
    for (int c=0;c<8;++c) acc += gv[c]*ow[c*8+j];
    lg[j] = acc;
  }
  float mx = lg[0];
  #pragma unroll
  for (int j=1;j<8;++j) mx = fmaxf(mx, lg[j]);
  float ssum = 0.0f;
  #pragma unroll
  for (int j=0;j<8;++j){ lg[j] = expf(lg[j]-mx); ssum += lg[j]; }
  float inv = 1.0f/ssum;
  #pragma unroll
  for (int j=0;j<8;++j) out[i*8+j] = lg[j]*inv;
}

// ================= FALLBACK (round-1 atomic path) =================
__global__ __launch_bounds__(256) void edge1_kernel(
    const float* __restrict__ x, const int* __restrict__ src, const int* __restrict__ dst,
    const float* __restrict__ sh, const float* __restrict__ elen,
    const float* __restrict__ wpw, const float* __restrict__ wpb,
    float* __restrict__ agg, CGTables cg)
{
  __shared__ float sw[176];
  for (int i=threadIdx.x;i<176;i+=256) sw[i] = (i<160) ? wpw[i] : wpb[i-160];
  __syncthreads();
  int e = blockIdx.x*256 + threadIdx.x;
  if (e >= NE) return;
  float len = elen[e];
  float lw[16];
  #pragma unroll
  for (int j=0;j<16;++j) lw[j] = sw[160+j];
  #pragma unroll
  for (int i=0;i<10;++i){
    float dd = len - (0.7f + (float)i*(1.0f/9.0f));
    float em = __expf(-50.0f*dd*dd);
    #pragma unroll
    for (int j=0;j<16;++j) lw[j] += em*sw[i*16+j];
  }
  float w = cutoff_w(len);
  int s = src[e], d = dst[e];
  float x0 = x[s];
  const float* shr = sh + (size_t)e*9;
  float sh0 = shr[0], sh1 = shr[1], sh2 = shr[2], sh3 = shr[3];
  float* ag = agg + (size_t)d*32;
  float b0 = cg.c000*x0*sh0*w;
  #pragma unroll
  for (int j=0;j<8;++j) unsafeAtomicAdd(ag+j, b0*lw[j]);
  #pragma unroll
  for (int o=0;o<3;++o){
    float s011 = cg.c011[o][0]*sh1 + cg.c011[o][1]*sh2 + cg.c011[o][2]*sh3;
    float bo = s011*x0*w;
    #pragma unroll
    for (int j=0;j<8;++j) unsafeAtomicAdd(ag+(1+o)*8+j, bo*lw[8+j]);
  }
}

__global__ __launch_bounds__(256) void edge2_kernel(
    const float* __restrict__ h, const int* __restrict__ src, const int* __restrict__ dst,
    const float* __restrict__ sh, const float* __restrict__ elen,
    const float* __restrict__ wpw, const float* __restrict__ wpb,
    float* __restrict__ agg, CGTables cg)
{
  __shared__ float sw[528];
  for (int i=threadIdx.x;i<528;i+=256) sw[i] = (i<480) ? wpw[i] : wpb[i-480];
  __syncthreads();
  int e = blockIdx.x*256 + threadIdx.x;
  if (e >= NE) return;
  float len = elen[e];
  float lw[48];
  #pragma unroll
  for (int j=0;j<48;++j) lw[j] = sw[480+j];
  #pragma unroll
  for (int i=0;i<10;++i){
    float dd = len - (0.7f + (float)i*(1.0f/9.0f));
    float em = __expf(-50.0f*dd*dd);
    #pragma unroll
    for (int j=0;j<48;++j) lw[j] += em*sw[i*48+j];
  }
  float w = cutoff_w(len);
  int s = src[e], d = dst[e];
  float shv[9];
  const float* shr = sh + (size_t)e*9;
  #pragma unroll
  for (int i=0;i<9;++i) shv[i] = shr[i];
  float sh0 = shv[0];
  float s011[3], k110[3], k111[3][3], k121[3][3];
  #pragma unroll
  for (int o=0;o<3;++o) s011[o] = cg.c011[o][0]*shv[1] + cg.c011[o][1]*shv[2] + cg.c011[o][2]*shv[3];
  #pragma unroll
  for (int a=0;a<3;++a) k110[a] = cg.c110[a][0]*shv[1] + cg.c110[a][1]*shv[2] + cg.c110[a][2]*shv[3];
  #pragma unroll
  for (int o=0;o<3;++o)
    #pragma unroll
    for (int a=0;a<3;++a)
      k111[o][a] = cg.c111[o][a][0]*shv[1] + cg.c111[o][a][1]*shv[2] + cg.c111[o][a][2]*shv[3];
  #pragma unroll
  for (int o=0;o<3;++o)
    #pragma unroll
    for (int a=0;a<3;++a){
      float acc = 0.0f;
      #pragma unroll
      for (int b=0;b<5;++b) acc += cg.c121[o][a][b]*shv[4+b];
      k121[o][a] = acc;
    }
  const float4* hr = reinterpret_cast<const float4*>(h + (size_t)s*32);
  float xs[32];
  #pragma unroll
  for (int i=0;i<8;++i){
    float4 q = hr[i];
    xs[i*4] = q.x; xs[i*4+1] = q.y; xs[i*4+2] = q.z; xs[i*4+3] = q.w;
  }
  float* ag = agg + (size_t)d*32;
  #pragma unroll
  for (int c=0;c<8;++c){
    float x0 = xs[c], x1 = xs[8+c], x2 = xs[16+c], x3 = xs[24+c];
    float r0 = cg.c000*sh0*x0*lw[c]
             + (k110[0]*x1 + k110[1]*x2 + k110[2]*x3)*lw[24+c];
    unsafeAtomicAdd(ag+c, r0*w);
    #pragma unroll
    for (int o=0;o<3;++o){
      float r = s011[o]*x0*lw[8+c]
              + (cg.c101[o][0]*x1 + cg.c101[o][1]*x2 + cg.c101[o][2]*x3)*sh0*lw[16+c]
              + (k111[o][0]*x1 + k111[o][1]*x2 + k111[o][2]*x3)*lw[32+c]
              + (k121[o][0]*x1 + k121[o][1]*x2 + k121[o][2]*x3)*lw[40+c];
      unsafeAtomicAdd(ag+(1+o)*8+c, r*w);
    }
  }
}

__global__ __launch_bounds__(256) void edge3_kernel(
    const float* __restrict__ h, const int* __restrict__ src, const int* __restrict__ dst,
    const float* __restrict__ sh, const float* __restrict__ elen,
    const float* __restrict__ wpw, const float* __restrict__ wpb,
    float* __restrict__ agg, CGTables cg)
{
  __shared__ float sw[176];
  for (int i=threadIdx.x;i<176;i+=256) sw[i] = (i<160) ? wpw[i] : wpb[i-160];
  __syncthreads();
  int e = blockIdx.x*256 + threadIdx.x;
  if (e >= NE) return;
  float len = elen[e];
  float lw[16];
  #pragma unroll
  for (int j=0;j<16;++j) lw[j] = sw[160+j];
  #pragma unroll
  for (int i=0;i<10;++i){
    float dd = len - (0.7f + (float)i*(1.0f/9.0f));
    float em = __expf(-50.0f*dd*dd);
    #pragma unroll
    for (int j=0;j<16;++j) lw[j] += em*sw[i*16+j];
  }
  float w = cutoff_w(len);
  int s = src[e], d = dst[e];
  const float* shr = sh + (size_t)e*9;
  float sh0 = shr[0], sh1 = shr[1], sh2 = shr[2], sh3 = shr[3];
  float k110[3];
  #pragma unroll
  for (int a=0;a<3;++a) k110[a] = cg.c110[a][0]*sh1 + cg.c110[a][1]*sh2 + cg.c110[a][2]*sh3;
  const float4* hr = reinterpret_cast<const float4*>(h + (size_t)s*32);
  float xs[32];
  #pragma unroll
  for (int i=0;i<8;++i){
    float4 q = hr[i];
    xs[i*4] = q.x; xs[i*4+1] = q.y; xs[i*4+2] = q.z; xs[i*4+3] = q.w;
  }
  float* ag = agg + (size_t)d*8;
  #pragma unroll
  for (int c=0;c<8;++c){
    float r = cg.c000*sh0*xs[c]*lw[c]
            + (k110[0]*xs[8+c] + k110[1]*xs[16+c] + k110[2]*xs[24+c])*lw[8+c];
    unsafeAtomicAdd(ag+c, r*w);
  }
}

__global__ __launch_bounds__(256) void node_fb_kernel(
    const float* __restrict__ agg, const float* __restrict__ si,
    float* __restrict__ out)
{
  __shared__ float s_si[128];
  if (threadIdx.x < 128) s_si[threadIdx.x] = si[threadIdx.x];
  __syncthreads();
  int idx = blockIdx.x*256 + threadIdx.x;
  if (idx >= NN*8) return;
  int n = idx >> 3, d = idx & 7;
  const float* ar = agg + (size_t)n*32;
  float y[4];
  #pragma unroll
  for (int m=0;m<4;++m){
    const float* sm = s_si + (m ? 64 : 0);
    float acc = 0.0f;
    #pragma unroll
    for (int c=0;c<8;++c) acc += ar[m*8+c]*sm[c*8+d];
    y[m] = acc;
  }
  float n0 = sqrtf(y[0]*y[0] + 1e-12f);
  float r0 = y[0]*(sspf(n0)/n0);
  float n1 = sqrtf(y[1]*y[1] + y[2]*y[2] + y[3]*y[3] + 1e-12f);
  float sc = sspf(n1)/n1;
  float* orow = out + (size_t)n*32;
  orow[d]      = r0;
  orow[8+d]    = y[1]*sc;
  orow[16+d]   = y[2]*sc;
  orow[24+d]   = y[3]*sc;
}

__global__ __launch_bounds__(256) void node3_fb_kernel(
    const float* __restrict__ agg, const float* __restrict__ si,
    const int* __restrict__ batch, float* __restrict__ g)
{
  __shared__ float s_si[64];
  if (threadIdx.x < 64) s_si[threadIdx.x] = si[threadIdx.x];
  __syncthreads();
  int n = blockIdx.x*256 + threadIdx.x;
  if (n >= NN) return;
  const float* ar = agg + (size_t)n*8;
  float av[8];
  #pragma unroll
  for (int c=0;c<8;++c) av[c] = ar[c];
  int b = batch[n];
  float* gr = g + (size_t)b*8;
  #pragma unroll
  for (int d=0;d<8;++d){
    float acc = 0.0f;
    #pragma unroll
    for (int c=0;c<8;++c) acc += av[c]*s_si[c*8+d];
    float v = acc / (1.0f + expf(-acc));
    unsafeAtomicAdd(gr+d, v);
  }
}

// ================= launch =================
extern "C" void kernel_launch(void* const* d_in, const int* in_sizes, int n_in,
                              void* d_out, int out_size, void* d_ws, size_t ws_size,
                              hipStream_t stream)
{
  const float* x     = (const float*)d_in[0];
  const int*   eidx  = (const int*)  d_in[1];
  const float* esh   = (const float*)d_in[2];
  const float* elen  = (const float*)d_in[3];
  const int*   batch = (const int*)  d_in[4];
  const float* wp1w  = (const float*)d_in[5];
  const float* wp1b  = (const float*)d_in[6];
  const float* wp2w  = (const float*)d_in[7];
  const float* wp2b  = (const float*)d_in[8];
  const float* wp3w  = (const float*)d_in[9];
  const float* wp3b  = (const float*)d_in[10];
  const float* si1   = (const float*)d_in[11];
  const float* si2   = (const float*)d_in[12];
  const float* si3   = (const float*)d_in[13];
  const float* outw  = (const float*)d_in[14];
  const float* outb  = (const float*)d_in[15];
  const int* src = eidx;
  const int* dst = eidx + NE;

  CGTables cg;
  build_cg_tables(cg);
  CGConsts K;
  build_cg_consts(cg, K);

  char* p = (char*)d_ws;
  auto carve = [&](size_t bytes) -> void* {
    void* r = (void*)p;
    p += ((bytes + 255)/256)*256;
    return r;
  };
  int*    rowptr = (int*)   carve((NN+1)*4);
  int*    perm   = (int*)   carve(NN*4);
  int*    bcnt   = (int*)   carve((NBUCK+1)*4);
  int*    bbase  = (int*)   carve((NBUCK+1)*4);
  int*    bclaim = (int*)   carve((NBUCK+1)*4);
  int*    dcnt   = (int*)   carve(256*4);
  int*    dcur   = (int*)   carve(256*4);
  float*  tab1   = (float*) carve(TBINS*16*4);
  float*  tab2   = (float*) carve(TB2*48*4);
  float*  tab3   = (float*) carve(TBINS*16*4);
  float*  G      = (float*) carve(512*4);
  float4* bufX   = (float4*)carve((size_t)NE*32);   // scatter dest; later aliased by B1/B2
  float4* bufY   = (float4*)carve((size_t)NE*32);   // sorted records (gather input)
  size_t need = (size_t)(p - (char*)d_ws);
  float* B1 = (float*)bufX;                          // 12.8MB, bufX dead after sortcopy
  float* B2 = (float*)bufX + (size_t)NN*32;          // next 12.8MB

  if (ws_size >= need){
    hipMemsetAsync(bcnt, 0, (NBUCK+1)*sizeof(int), stream);
    hipMemsetAsync(dcnt, 0, 256*sizeof(int), stream);
    hipMemsetAsync(G, 0, 512*sizeof(float), stream);
    lwtab_kernel<<<(TBINS*16+255)/256, 256, 0, stream>>>(wp1w, wp1b, 2, TBINS, tab1);
    lwtab_kernel<<<(TB2*48+255)/256, 256, 0, stream>>>(wp2w, wp2b, 6, TB2, tab2);
    lwtab_kernel<<<(TBINS*16+255)/256, 256, 0, stream>>>(wp3w, wp3b, 2, TBINS, tab3);
    bhist_kernel<<<SCB, 1024, 0, stream>>>(dst, bcnt);
    bscan_kernel<<<1, 1024, 0, stream>>>(bcnt, bbase, bclaim);
    scatter_rec_kernel<<<SCB, 256, 0, stream>>>(src, dst, esh, elen, x, bclaim, bufX, K);
    sortcopy_kernel<<<NBUCK, 512, 0, stream>>>(bufX, bbase, bufY, rowptr);
    deg_hist_kernel<<<NBLK_SCAN, 256, 0, stream>>>(rowptr, dcnt);
    deg_scan_kernel<<<1, 256, 0, stream>>>(dcnt, dcur);
    deg_scatter_kernel<<<NBLK_SCAN, 256, 0, stream>>>(rowptr, dcur, perm);
    gather1_kernel<<<NBLK_N8, 256, 0, stream>>>(rowptr, perm, bufY, tab1, si1, B1, K);
    gather2_kernel<<<NBLK_N8, 256, 0, stream>>>(B1, rowptr, perm, bufY, tab2, si2, B2, K);
    gather3_kernel<<<NBLK_N8, 256, 0, stream>>>(B2, rowptr, perm, bufY, tab3, si3, batch, G, K);
    final_kernel<<<1, 64, 0, stream>>>(G, outw, outb, (float*)d_out);
  } else {
    // fallback: round-1 atomic path (~29 MB)
    float* A  = (float*)d_ws;
    float* Bf = A + (size_t)NN*32;
    float* Cf = Bf + (size_t)NN*32;
    float* Gf = Cf + (size_t)NN*8;
    hipMemsetAsync(A, 0, (size_t)NN*32*sizeof(float), stream);
    edge1_kernel<<<NBLK_E, 256, 0, stream>>>(x, src, dst, esh, elen, wp1w, wp1b, A, cg);
    node_fb_kernel<<<(NN*8+255)/256, 256, 0, stream>>>(A, si1, Bf);
    hipMemsetAsync(A, 0, (size_t)NN*32*sizeof(float), stream);
    edge2_kernel<<<NBLK_E, 256, 0, stream>>>(Bf, src, dst, esh, elen, wp2w, wp2b, A, cg);
    node_fb_kernel<<<(NN*8+255)/256, 256, 0, stream>>>(A, si2, Bf);
    hipMemsetAsync(Cf, 0, (size_t)NN*8*sizeof(float), stream);
    edge3_kernel<<<NBLK_E, 256, 0, stream>>>(Bf, src, dst, esh, elen, wp3w, wp3b, Cf, cg);
    hipMemsetAsync(Gf, 0, (size_t)NG*8*sizeof(float), stream);
    node3_fb_kernel<<<(NN+255)/256, 256, 0, stream>>>(Cf, si3, batch, Gf);
    final_kernel<<<1, 64, 0, stream>>>(Gf, outw, outb, (float*)d_out);
  }
}

// Round 18
// 252.475 us; speedup vs baseline: 1.0596x; 1.0596x over previous
//
#include <hip/hip_runtime.h>
#include <hip/hip_fp16.h>
#include <math.h>
#include <complex>

#define NN 100000
#define NE 1600000
#define NG 64
#define NBUCK 782          // ceil(NN/128); bucket = dst >> 7
#define SCB 256
#define SEB 6250           // SCB*SEB == NE
#define TBINS 256          // layers 1,3 table bins
#define TB2   128          // layer 2 table bins (LDS budget)
#define MAXB  2560         // max edges per bucket
#define NBLK_E   6250
#define NBLK_N8  3125
#define NBLK_SCAN 391

// ---------------- CG tables (host) ----------------
struct CGTables {
  float c000;
  float c011[3][3];
  float c101[3][3];
  float c110[3][3];
  float c111[3][3][3];
  float c121[3][3][5];
};
struct CGConsts {
  float c000;
  float l011, l101, l110, l111;
  float s121[5][5];
};

static double hfact(int n){ double r=1.0; for(int i=2;i<=n;++i) r*=(double)i; return r; }

static double host_cgc(int j1,int m1,int j2,int m2,int j3,int m3){
  if (m1+m2 != m3) return 0.0;
  double pre = sqrt((2.0*j3+1.0)*hfact(j3+j1-j2)*hfact(j3-j1+j2)*hfact(j1+j2-j3)/hfact(j1+j2+j3+1));
  pre *= sqrt(hfact(j3+m3)*hfact(j3-m3)*hfact(j1-m1)*hfact(j1+m1)*hfact(j2-m2)*hfact(j2+m2));
  int k0 = 0; if (j2-j3-m1 > k0) k0 = j2-j3-m1; if (j1-j3+m2 > k0) k0 = j1-j3+m2;
  int k1 = j1+j2-j3; if (j1-m1 < k1) k1 = j1-m1; if (j2+m2 < k1) k1 = j2+m2;
  double s = 0.0;
  for (int k=k0;k<=k1;++k){
    double t = 1.0/(hfact(k)*hfact(j1+j2-j3-k)*hfact(j1-m1-k)*hfact(j2+m2-k)*hfact(j3-j2+m1+k)*hfact(j3-j1-m2+k));
    s += (k&1) ? -t : t;
  }
  return pre*s;
}

typedef std::complex<double> cd;

static void host_u(int l, cd U[5][5]){
  for (int a=0;a<5;++a) for (int b=0;b<5;++b) U[a][b] = 0.0;
  U[l][l] = 1.0;
  const double is2 = 1.0/sqrt(2.0);
  for (int m=1;m<=l;++m){
    double sgn = (m&1) ? -1.0 : 1.0;
    U[l+m][l+m] = sgn*is2;
    U[l+m][l-m] = is2;
    U[l-m][l-m] = cd(0.0, is2);
    U[l-m][l+m] = cd(0.0, -sgn*is2);
  }
}

static void host_real_cg(int l1,int l2,int l3, float* out){
  cd U1[5][5], U2[5][5], U3[5][5];
  host_u(l1,U1); host_u(l2,U2); host_u(l3,U3);
  int n1=2*l1+1, n2=2*l2+1, n3=2*l3+1;
  double cgt[5][5][5];
  for (int i=0;i<5;++i) for (int j=0;j<5;++j) for (int k=0;k<5;++k) cgt[i][j][k]=0.0;
  for (int m1=-l1;m1<=l1;++m1) for (int m2=-l2;m2<=l2;++m2){
    int m3 = m1+m2;
    if (m3 >= -l3 && m3 <= l3) cgt[l1+m1][l2+m2][l3+m3] = host_cgc(l1,m1,l2,m2,l3,m3);
  }
  cd W[5][5][5];
  double sre=0.0, sim=0.0;
  for (int c=0;c<n3;++c) for (int a=0;a<n1;++a) for (int b=0;b<n2;++b){
    cd acc = 0.0;
    for (int i=0;i<n1;++i) for (int j=0;j<n2;++j) for (int k=0;k<n3;++k)
      acc += U1[a][i]*U2[b][j]*std::conj(U3[c][k])*cgt[i][j][k];
    W[c][a][b] = acc;
    sre += fabs(acc.real()); sim += fabs(acc.imag());
  }
  bool use_re = (sre >= sim);
  for (int c=0;c<n3;++c) for (int a=0;a<n1;++a) for (int b=0;b<n2;++b)
    out[(c*n1+a)*n2+b] = (float)(use_re ? W[c][a][b].real() : W[c][a][b].imag());
}

static void build_cg_tables(CGTables& t){
  float w000[1];  host_real_cg(0,0,0,w000); t.c000 = w000[0];
  float w011[9];  host_real_cg(0,1,1,w011);
  for (int o=0;o<3;++o) for (int b=0;b<3;++b) t.c011[o][b] = w011[o*3+b];
  float w101[9];  host_real_cg(1,0,1,w101);
  for (int o=0;o<3;++o) for (int a=0;a<3;++a) t.c101[o][a] = w101[o*3+a];
  float w110[9];  host_real_cg(1,1,0,w110);
  for (int a=0;a<3;++a) for (int b=0;b<3;++b) t.c110[a][b] = w110[a*3+b];
  float w111[27]; host_real_cg(1,1,1,w111);
  for (int o=0;o<3;++o) for (int a=0;a<3;++a) for (int b=0;b<3;++b) t.c111[o][a][b] = w111[(o*3+a)*3+b];
  float w121[45]; host_real_cg(1,2,1,w121);
  for (int o=0;o<3;++o) for (int a=0;a<3;++a) for (int b=0;b<5;++b) t.c121[o][a][b] = w121[(o*3+a)*5+b];
}

static void build_cg_consts(const CGTables& t, CGConsts& K){
  K.c000 = t.c000;
  K.l011 = t.c011[0][0];
  K.l101 = t.c101[0][0];
  K.l110 = t.c110[0][0];
  K.l111 = t.c111[0][1][2];
  const int pi[5] = {0,0,0,1,1};
  const int pj[5] = {0,1,2,1,2};
  for (int p=0;p<5;++p)
    for (int b=0;b<5;++b)
      K.s121[p][b] = 0.5f*(t.c121[pi[p]][pj[p]][b] + t.c121[pj[p]][pi[p]][b]);
}

// ---------------- device helpers ----------------
__device__ __forceinline__ float sspf(float v){
  float sp = (v > 30.0f) ? v : log1pf(expf(v));
  return sp - 0.69314718055994531f;
}

__device__ __forceinline__ float cutoff_w(float len){
  float u = len * (1.0f/1.5f);
  float u2 = u*u, u6 = u2*u2*u2, u7 = u6*u, u8 = u7*u;
  float cut = 1.0f - 28.0f*u6 + 48.0f*u7 - 21.0f*u8;
  return (u < 1.0f) ? cut : 0.0f;
}

__device__ __forceinline__ float pack2h(float a, float b){
  __half2 h = __floats2half2_rn(a, b);
  return *reinterpret_cast<float*>(&h);
}
__device__ __forceinline__ float2 unpack2h(float f){
  __half2 h = *reinterpret_cast<__half2*>(&f);
  return __half22float2(h);
}

// ================= radial-weight table build =================
__global__ __launch_bounds__(256) void lwtab_kernel(
    const float* __restrict__ wpw, const float* __restrict__ wpb,
    int NP, int bins, float* __restrict__ tab)
{
  int idx = blockIdx.x*256 + threadIdx.x;
  int tot = bins*NP*8;
  if (idx >= tot) return;
  int stride = NP*8;
  int bin = idx / stride;
  int r = idx - bin*stride;
  float len = (1.5f/(bins-1)) * bin;
  float v = wpb[r];
  #pragma unroll
  for (int i=0;i<10;++i){
    float dd = len - (0.7f + (float)i*(1.0f/9.0f));
    v = fmaf(wpw[i*stride + r], __expf(-50.0f*dd*dd), v);
  }
  tab[idx] = v;
}

// ================= bucket hist / scan =================
__global__ __launch_bounds__(1024) void bhist_kernel(const int* __restrict__ dst, int* __restrict__ bcnt){
  __shared__ int cnt[NBUCK];
  for (int j=threadIdx.x; j<NBUCK; j+=1024) cnt[j] = 0;
  __syncthreads();
  int base = blockIdx.x * SEB;
  for (int i=threadIdx.x; i<SEB; i+=1024)
    atomicAdd(&cnt[dst[base+i] >> 7], 1);
  __syncthreads();
  for (int j=threadIdx.x; j<NBUCK; j+=1024)
    if (cnt[j]) atomicAdd(&bcnt[j], cnt[j]);
}

__global__ __launch_bounds__(1024) void bscan_kernel(const int* __restrict__ bcnt,
                                                     int* __restrict__ bbase, int* __restrict__ bclaim){
  __shared__ int s[1024];
  int t = threadIdx.x;
  int v = (t < NBUCK) ? bcnt[t] : 0;
  s[t] = v; __syncthreads();
  for (int off=1; off<1024; off<<=1){
    int u = (t >= off) ? s[t-off] : 0;
    __syncthreads();
    s[t] += u;
    __syncthreads();
  }
  if (t < NBUCK){
    int excl = s[t] - v;
    bbase[t] = excl;
    bclaim[t] = excl;
    if (t == NBUCK-1) bbase[NBUCK] = excl + v;
  }
}

// ================= bucketed record scatter (1024 threads, 256 windows — R14 best) =================
// 32B record:
//  q0 = (sn | dl<<20, len, h2(wsh0,wshx), h2(wshy,wshz))
//  q1 = (h2(S00,S01), h2(S02,S11), S12, x0)
__global__ __launch_bounds__(1024) void scatter_rec_kernel(
    const int* __restrict__ src, const int* __restrict__ dst,
    const float* __restrict__ sh, const float* __restrict__ elen,
    const float* __restrict__ x,
    int* __restrict__ bclaim, float4* __restrict__ rec, CGConsts K)
{
  __shared__ int cnt[NBUCK];
  __shared__ int bs[NBUCK];
  for (int j=threadIdx.x; j<NBUCK; j+=1024) cnt[j] = 0;
  __syncthreads();
  int base = blockIdx.x * SEB;
  for (int i=threadIdx.x; i<SEB; i+=1024)
    atomicAdd(&cnt[dst[base+i] >> 7], 1);
  __syncthreads();
  for (int j=threadIdx.x; j<NBUCK; j+=1024){
    int c = cnt[j];
    if (c) bs[j] = atomicAdd(&bclaim[j], c);
    cnt[j] = 0;
  }
  __syncthreads();
  for (int i=threadIdx.x; i<SEB; i+=1024){
    int e = base + i;
    int d = dst[e];
    int b = d >> 7;
    int off = atomicAdd(&cnt[b], 1);
    int slot = bs[b] + off;
    float len = elen[e];
    float w = cutoff_w(len);
    const float* shr = sh + (size_t)e*9;
    float sh0 = shr[0]*w, shx = shr[1]*w, shy = shr[2]*w, shz = shr[3]*w;
    float b0 = shr[4], b1 = shr[5], b2 = shr[6], b3 = shr[7], b4 = shr[8];
    float S[5];
    #pragma unroll
    for (int p=0;p<5;++p)
      S[p] = (K.s121[p][0]*b0 + K.s121[p][1]*b1 + K.s121[p][2]*b2 + K.s121[p][3]*b3 + K.s121[p][4]*b4)*w;
    int sn = src[e];
    float x0 = x[sn];
    int packed = sn | ((d & 127) << 20);
    float4* rp = rec + (size_t)slot*2;
    rp[0] = make_float4(__int_as_float(packed), len, pack2h(sh0, shx), pack2h(shy, shz));
    rp[1] = make_float4(pack2h(S[0], S[1]), pack2h(S[2], S[3]), S[4], x0);
  }
}

// ================= per-bucket sort-copy (L2-hot window) + rowptr =================
__global__ __launch_bounds__(512) void sortcopy_kernel(
    const float4* __restrict__ recin, const int* __restrict__ bbase,
    float4* __restrict__ recout, int* __restrict__ rowptr)
{
  __shared__ int hist[128], offs[128], cur[128];
  __shared__ short outmap[MAXB];
  int b = blockIdx.x;
  int e0 = bbase[b], e1 = bbase[b+1];
  int cnt = e1 - e0;
  int t = threadIdx.x;
  if (t < 128) hist[t] = 0;
  __syncthreads();
  for (int i=t; i<cnt; i+=512){
    int packed = __float_as_int(recin[(size_t)(e0+i)*2].x);
    atomicAdd(&hist[packed >> 20], 1);
  }
  __syncthreads();
  if (t < 128) offs[t] = hist[t];
  __syncthreads();
  for (int off=1; off<128; off<<=1){
    int v = (t < 128 && t >= off) ? offs[t-off] : 0;
    __syncthreads();
    if (t < 128) offs[t] += v;
    __syncthreads();
  }
  int n0 = b << 7;
  int nn = NN - n0; if (nn > 128) nn = 128;
  if (t < 128){
    int excl = offs[t] - hist[t];
    cur[t] = excl;
    if (t < nn) rowptr[n0+t] = e0 + excl;
  }
  if (b == NBUCK-1 && t == 0) rowptr[NN] = NE;
  __syncthreads();
  for (int i=t; i<cnt; i+=512){
    int packed = __float_as_int(recin[(size_t)(e0+i)*2].x);
    int r = atomicAdd(&cur[packed >> 20], 1);
    outmap[r] = (short)i;
  }
  __syncthreads();
  for (int o=t; o<cnt; o+=512){
    int j = outmap[o];
    const float4* rin = recin + (size_t)(e0+j)*2;
    float4* rout = recout + (size_t)(e0+o)*2;
    float4 a = rin[0], bq = rin[1];
    rout[0] = a; rout[1] = bq;
  }
}

// ================= degree binning =================
__global__ __launch_bounds__(256) void deg_hist_kernel(const int* __restrict__ rowptr, int* __restrict__ dcnt){
  __shared__ int lb[256];
  lb[threadIdx.x] = 0; __syncthreads();
  int n = blockIdx.x*256 + threadIdx.x;
  if (n < NN){
    int d = rowptr[n+1]-rowptr[n]; if (d > 255) d = 255;
    atomicAdd(&lb[d], 1);
  }
  __syncthreads();
  if (lb[threadIdx.x]) atomicAdd(&dcnt[threadIdx.x], lb[threadIdx.x]);
}

__global__ void deg_scan_kernel(const int* __restrict__ dcnt, int* __restrict__ dcur){
  __shared__ int s[256];
  int t = threadIdx.x;
  int v = dcnt[t];
  s[t] = v; __syncthreads();
  for (int off=1; off<256; off<<=1){
    int u = (t >= off) ? s[t-off] : 0;
    __syncthreads();
    s[t] += u;
    __syncthreads();
  }
  dcur[t] = s[t] - v;
}

__global__ __launch_bounds__(256) void deg_scatter_kernel(const int* __restrict__ rowptr,
                                                          int* __restrict__ dcur, int* __restrict__ perm){
  __shared__ int lcnt[256];
  __shared__ int lbase[256];
  int t = threadIdx.x;
  lcnt[t] = 0;
  __syncthreads();
  int n = blockIdx.x*256 + t;
  int d = 0, lrank = 0;
  bool valid = (n < NN);
  if (valid){
    d = rowptr[n+1]-rowptr[n]; if (d > 255) d = 255;
    lrank = atomicAdd(&lcnt[d], 1);
  }
  __syncthreads();
  int cnt = lcnt[t];
  if (cnt > 0) lbase[t] = atomicAdd(&dcur[t], cnt);
  __syncthreads();
  if (valid) perm[lbase[d] + lrank] = n;
}

// ================= gather layer 1 =================
__global__ __launch_bounds__(256) void gather1_kernel(
    const int* __restrict__ rowptr, const int* __restrict__ perm,
    const float4* __restrict__ rec, const float* __restrict__ tab,
    const float* __restrict__ si, float* __restrict__ out, CGConsts K)
{
  __shared__ float lwt[TBINS*16];
  for (int i=threadIdx.x; i<TBINS*16; i+=256) lwt[i] = tab[i];
  __syncthreads();
  int gid = blockIdx.x*256 + threadIdx.x;
  int c = gid & 7;
  int n = perm[gid >> 3];
  int r0 = rowptr[n], r1 = rowptr[n+1];
  float a0=0.f, a1=0.f, a2=0.f, a3=0.f;
  #pragma unroll 2
  for (int s=r0; s<r1; ++s){
    const float4* rp = rec + (size_t)s*2;
    float4 q0 = rp[0];
    float4 q1 = rp[1];
    float len = q0.y;
    float2 s01 = unpack2h(q0.z);
    float2 s23 = unpack2h(q0.w);
    float sh0 = s01.x, shx = s01.y, shy = s23.x, shz = s23.y;
    float x0 = q1.w;
    float fb = len * ((TBINS-1)/1.5f);
    int bin = (int)fb; if (bin > TBINS-2) bin = TBINS-2;
    float fr = fb - (float)bin;
    int tb = bin*16 + c;
    float lw0 = fmaf(fr, lwt[tb+16]-lwt[tb], lwt[tb]);
    float lw1 = fmaf(fr, lwt[tb+24]-lwt[tb+8], lwt[tb+8]);
    a0 = fmaf(K.c000*sh0, x0*lw0, a0);
    float t = K.l011*x0*lw1;
    a1 = fmaf(t, shx, a1); a2 = fmaf(t, shy, a2); a3 = fmaf(t, shz, a3);
  }
  float z0=0.f, z1=0.f, z2=0.f, z3=0.f;
  #pragma unroll
  for (int k=0;k<8;++k){
    float y0 = __shfl(a0,k,8), y1 = __shfl(a1,k,8), y2 = __shfl(a2,k,8), y3 = __shfl(a3,k,8);
    float w0 = si[k*8+c], w1 = si[64+k*8+c];
    z0 = fmaf(y0,w0,z0); z1 = fmaf(y1,w1,z1); z2 = fmaf(y2,w1,z2); z3 = fmaf(y3,w1,z3);
  }
  float n0 = sqrtf(z0*z0 + 1e-12f);
  float r0v = z0*(sspf(n0)/n0);
  float nv = sqrtf(z1*z1 + z2*z2 + z3*z3 + 1e-12f);
  float sc = sspf(nv)/nv;
  float4 o = make_float4(r0v, z1*sc, z2*sc, z3*sc);
  *reinterpret_cast<float4*>(out + ((size_t)n*8 + c)*4) = o;   // layout [n][c][m]
}

// ================= gather layer 2 (TB2-bin table) =================
__global__ __launch_bounds__(256) void gather2_kernel(
    const float* __restrict__ hin,           // [NN][8][4]
    const int* __restrict__ rowptr, const int* __restrict__ perm,
    const float4* __restrict__ rec, const float* __restrict__ tab,
    const float* __restrict__ si, float* __restrict__ out, CGConsts K)
{
  __shared__ float lwt[TB2*48];
  for (int i=threadIdx.x; i<TB2*48; i+=256) lwt[i] = tab[i];
  __syncthreads();
  int gid = blockIdx.x*256 + threadIdx.x;
  int c = gid & 7;
  int n = perm[gid >> 3];
  int r0 = rowptr[n], r1 = rowptr[n+1];
  float a0=0.f, a1=0.f, a2=0.f, a3=0.f;
  #pragma unroll 2
  for (int s=r0; s<r1; ++s){
    const float4* rp = rec + (size_t)s*2;
    float4 q0 = rp[0];
    float4 q1 = rp[1];
    int sn = __float_as_int(q0.x) & 0xFFFFF;
    float len = q0.y;
    float2 s01 = unpack2h(q0.z);
    float2 s23 = unpack2h(q0.w);
    float sh0 = s01.x, shx = s01.y, shy = s23.x, shz = s23.y;
    float2 Sa = unpack2h(q1.x);
    float2 Sb = unpack2h(q1.y);
    float S00 = Sa.x, S01 = Sa.y, S02 = Sb.x, S11 = Sb.y, S12 = q1.z;
    float S22 = -S00 - S11;
    float4 hv = *reinterpret_cast<const float4*>(hin + ((size_t)sn*8 + c)*4);
    float x0 = hv.x, xa0 = hv.y, xa1 = hv.z, xa2 = hv.w;
    float fb = len * ((TB2-1)/1.5f);
    int bin = (int)fb; if (bin > TB2-2) bin = TB2-2;
    float fr = fb - (float)bin;
    int tb = bin*48 + c;
    float lw[6];
    #pragma unroll
    for (int p=0;p<6;++p){
      float t0v = lwt[tb + p*8];
      float t1v = lwt[tb + 48 + p*8];
      lw[p] = fmaf(fr, t1v - t0v, t0v);
    }
    float shdotx = shx*xa0 + shy*xa1 + shz*xa2;
    a0 += K.c000*sh0*x0*lw[0] + K.l110*shdotx*lw[3];
    float t011 = K.l011*x0*lw[1];
    float t101 = K.l101*sh0*lw[2];
    float l4 = K.l111*lw[4];
    float sx0 = S00*xa0 + S01*xa1 + S02*xa2;
    float sx1 = S01*xa0 + S11*xa1 + S12*xa2;
    float sx2 = S02*xa0 + S12*xa1 + S22*xa2;
    a1 += t011*shx + t101*xa0 + l4*(xa1*shz - xa2*shy) + sx0*lw[5];
    a2 += t011*shy + t101*xa1 + l4*(xa2*shx - xa0*shz) + sx1*lw[5];
    a3 += t011*shz + t101*xa2 + l4*(xa0*shy - xa1*shx) + sx2*lw[5];
  }
  float z0=0.f, z1=0.f, z2=0.f, z3=0.f;
  #pragma unroll
  for (int k=0;k<8;++k){
    float y0 = __shfl(a0,k,8), y1 = __shfl(a1,k,8), y2 = __shfl(a2,k,8), y3 = __shfl(a3,k,8);
    float w0 = si[k*8+c], w1 = si[64+k*8+c];
    z0 = fmaf(y0,w0,z0); z1 = fmaf(y1,w1,z1); z2 = fmaf(y2,w1,z2); z3 = fmaf(y3,w1,z3);
  }
  float n0 = sqrtf(z0*z0 + 1e-12f);
  float r0v = z0*(sspf(n0)/n0);
  float nv = sqrtf(z1*z1 + z2*z2 + z3*z3 + 1e-12f);
  float sc = sspf(nv)/nv;
  float4 o = make_float4(r0v, z1*sc, z2*sc, z3*sc);
  *reinterpret_cast<float4*>(out + ((size_t)n*8 + c)*4) = o;
}

// ================= gather layer 3 + pool (reads q0 only) =================
__global__ __launch_bounds__(256) void gather3_kernel(
    const float* __restrict__ hin, const int* __restrict__ rowptr, const int* __restrict__ perm,
    const float4* __restrict__ rec, const float* __restrict__ tab,
    const float* __restrict__ si, const int* __restrict__ batch,
    float* __restrict__ G, CGConsts K)
{
  __shared__ float lwt[TBINS*16];
  __shared__ float lg[512];
  for (int i=threadIdx.x; i<TBINS*16; i+=256) lwt[i] = tab[i];
  lg[threadIdx.x] = 0.f; lg[256+threadIdx.x] = 0.f;
  __syncthreads();
  int gid = blockIdx.x*256 + threadIdx.x;
  int c = gid & 7;
  int n = perm[gid >> 3];
  int r0 = rowptr[n], r1 = rowptr[n+1];
  float acc = 0.f;
  #pragma unroll 2
  for (int s=r0; s<r1; ++s){
    float4 q0 = rec[(size_t)s*2];
    int sn = __float_as_int(q0.x) & 0xFFFFF;
    float len = q0.y;
    float2 s01 = unpack2h(q0.z);
    float2 s23 = unpack2h(q0.w);
    float sh0 = s01.x, shx = s01.y, shy = s23.x, shz = s23.y;
    float4 hv = *reinterpret_cast<const float4*>(hin + ((size_t)sn*8 + c)*4);
    float fb = len * ((TBINS-1)/1.5f);
    int bin = (int)fb; if (bin > TBINS-2) bin = TBINS-2;
    float fr = fb - (float)bin;
    int tb = bin*16 + c;
    float lw0 = fmaf(fr, lwt[tb+16]-lwt[tb], lwt[tb]);
    float lw1 = fmaf(fr, lwt[tb+24]-lwt[tb+8], lwt[tb+8]);
    float shdotx = shx*hv.y + shy*hv.z + shz*hv.w;
    acc += K.c000*sh0*hv.x*lw0 + K.l110*shdotx*lw1;
  }
  float z = 0.f;
  #pragma unroll
  for (int k=0;k<8;++k){
    float y = __shfl(acc,k,8);
    z = fmaf(y, si[k*8+c], z);
  }
  float v = z / (1.0f + expf(-z));   // silu
  atomicAdd(&lg[batch[n]*8 + c], v);
  __syncthreads();
  int t = threadIdx.x;
  float v0 = lg[t];     if (v0 != 0.f) unsafeAtomicAdd(&G[t], v0);
  float v1 = lg[256+t]; if (v1 != 0.f) unsafeAtomicAdd(&G[256+t], v1);
}

// ================= final =================
__global__ void final_kernel(
    const float* __restrict__ g, const float* __restrict__ ow,
    const float* __restrict__ ob, float* __restrict__ out)
{
  int i = threadIdx.x;
  if (i >= NG) return;
  float gv[8];
  #pragma unroll
  for (int c=0;c<8;++c) gv[c] = g[i*8+c];
  float lg[8];
  #pragma unroll
  for (int j=0;j<8;++j){
    float acc = ob[j];
    #pragma unroll
    for (int c=0;c<8;++c) acc += gv[c]*ow[c*8+j];
    lg[j] = acc;
  }
  float mx = lg[0];
  #pragma unroll
  for (int j=1;j<8;++j) mx = fmaxf(mx, lg[j]);
  float ssum = 0.0f;
  #pragma unroll
  for (int j=0;j<8;++j){ lg[j] = expf(lg[j]-mx); ssum += lg[j]; }
  float inv = 1.0f/ssum;
  #pragma unroll
  for (int j=0;j<8;++j) out[i*8+j] = lg[j]*inv;
}

// ================= FALLBACK (round-1 atomic path) =================
__global__ __launch_bounds__(256) void edge1_kernel(
    const float* __restrict__ x, const int* __restrict__ src, const int* __restrict__ dst,
    const float* __restrict__ sh, const float* __restrict__ elen,
    const float* __restrict__ wpw, const float* __restrict__ wpb,
    float* __restrict__ agg, CGTables cg)
{
  __shared__ float sw[176];
  for (int i=threadIdx.x;i<176;i+=256) sw[i] = (i<160) ? wpw[i] : wpb[i-160];
  __syncthreads();
  int e = blockIdx.x*256 + threadIdx.x;
  if (e >= NE) return;
  float len = elen[e];
  float lw[16];
  #pragma unroll
  for (int j=0;j<16;++j) lw[j] = sw[160+j];
  #pragma unroll
  for (int i=0;i<10;++i){
    float dd = len - (0.7f + (float)i*(1.0f/9.0f));
    float em = __expf(-50.0f*dd*dd);
    #pragma unroll
    for (int j=0;j<16;++j) lw[j] += em*sw[i*16+j];
  }
  float w = cutoff_w(len);
  int s = src[e], d = dst[e];
  float x0 = x[s];
  const float* shr = sh + (size_t)e*9;
  float sh0 = shr[0], sh1 = shr[1], sh2 = shr[2], sh3 = shr[3];
  float* ag = agg + (size_t)d*32;
  float b0 = cg.c000*x0*sh0*w;
  #pragma unroll
  for (int j=0;j<8;++j) unsafeAtomicAdd(ag+j, b0*lw[j]);
  #pragma unroll
  for (int o=0;o<3;++o){
    float s011 = cg.c011[o][0]*sh1 + cg.c011[o][1]*sh2 + cg.c011[o][2]*sh3;
    float bo = s011*x0*w;
    #pragma unroll
    for (int j=0;j<8;++j) unsafeAtomicAdd(ag+(1+o)*8+j, bo*lw[8+j]);
  }
}

__global__ __launch_bounds__(256) void edge2_kernel(
    const float* __restrict__ h, const int* __restrict__ src, const int* __restrict__ dst,
    const float* __restrict__ sh, const float* __restrict__ elen,
    const float* __restrict__ wpw, const float* __restrict__ wpb,
    float* __restrict__ agg, CGTables cg)
{
  __shared__ float sw[528];
  for (int i=threadIdx.x;i<528;i+=256) sw[i] = (i<480) ? wpw[i] : wpb[i-480];
  __syncthreads();
  int e = blockIdx.x*256 + threadIdx.x;
  if (e >= NE) return;
  float len = elen[e];
  float lw[48];
  #pragma unroll
  for (int j=0;j<48;++j) lw[j] = sw[480+j];
  #pragma unroll
  for (int i=0;i<10;++i){
    float dd = len - (0.7f + (float)i*(1.0f/9.0f));
    float em = __expf(-50.0f*dd*dd);
    #pragma unroll
    for (int j=0;j<48;++j) lw[j] += em*sw[i*48+j];
  }
  float w = cutoff_w(len);
  int s = src[e], d = dst[e];
  float shv[9];
  const float* shr = sh + (size_t)e*9;
  #pragma unroll
  for (int i=0;i<9;++i) shv[i] = shr[i];
  float sh0 = shv[0];
  float s011[3], k110[3], k111[3][3], k121[3][3];
  #pragma unroll
  for (int o=0;o<3;++o) s011[o] = cg.c011[o][0]*shv[1] + cg.c011[o][1]*shv[2] + cg.c011[o][2]*shv[3];
  #pragma unroll
  for (int a=0;a<3;++a) k110[a] = cg.c110[a][0]*shv[1] + cg.c110[a][1]*shv[2] + cg.c110[a][2]*shv[3];
  #pragma unroll
  for (int o=0;o<3;++o)
    #pragma unroll
    for (int a=0;a<3;++a)
      k111[o][a] = cg.c111[o][a][0]*shv[1] + cg.c111[o][a][1]*shv[2] + cg.c111[o][a][2]*shv[3];
  #pragma unroll
  for (int o=0;o<3;++o)
    #pragma unroll
    for (int a=0;a<3;++a){
      float acc = 0.0f;
      #pragma unroll
      for (int b=0;b<5;++b) acc += cg.c121[o][a][b]*shv[4+b];
      k121[o][a] = acc;
    }
  const float4* hr = reinterpret_cast<const float4*>(h + (size_t)s*32);
  float xs[32];
  #pragma unroll
  for (int i=0;i<8;++i){
    float4 q = hr[i];
    xs[i*4] = q.x; xs[i*4+1] = q.y; xs[i*4+2] = q.z; xs[i*4+3] = q.w;
  }
  float* ag = agg + (size_t)d*32;
  #pragma unroll
  for (int c=0;c<8;++c){
    float x0 = xs[c], x1 = xs[8+c], x2 = xs[16+c], x3 = xs[24+c];
    float r0 = cg.c000*sh0*x0*lw[c]
             + (k110[0]*x1 + k110[1]*x2 + k110[2]*x3)*lw[24+c];
    unsafeAtomicAdd(ag+c, r0*w);
    #pragma unroll
    for (int o=0;o<3;++o){
      float r = s011[o]*x0*lw[8+c]
              + (cg.c101[o][0]*x1 + cg.c101[o][1]*x2 + cg.c101[o][2]*x3)*sh0*lw[16+c]
              + (k111[o][0]*x1 + k111[o][1]*x2 + k111[o][2]*x3)*lw[32+c]
              + (k121[o][0]*x1 + k121[o][1]*x2 + k121[o][2]*x3)*lw[40+c];
      unsafeAtomicAdd(ag+(1+o)*8+c, r*w);
    }
  }
}

__global__ __launch_bounds__(256) void edge3_kernel(
    const float* __restrict__ h, const int* __restrict__ src, const int* __restrict__ dst,
    const float* __restrict__ sh, const float* __restrict__ elen,
    const float* __restrict__ wpw, const float* __restrict__ wpb,
    float* __restrict__ agg, CGTables cg)
{
  __shared__ float sw[176];
  for (int i=threadIdx.x;i<176;i+=256) sw[i] = (i<160) ? wpw[i] : wpb[i-160];
  __syncthreads();
  int e = blockIdx.x*256 + threadIdx.x;
  if (e >= NE) return;
  float len = elen[e];
  float lw[16];
  #pragma unroll
  for (int j=0;j<16;++j) lw[j] = sw[160+j];
  #pragma unroll
  for (int i=0;i<10;++i){
    float dd = len - (0.7f + (float)i*(1.0f/9.0f));
    float em = __expf(-50.0f*dd*dd);
    #pragma unroll
    for (int j=0;j<16;++j) lw[j] += em*sw[i*16+j];
  }
  float w = cutoff_w(len);
  int s = src[e], d = dst[e];
  const float* shr = sh + (size_t)e*9;
  float sh0 = shr[0], sh1 = shr[1], sh2 = shr[2], sh3 = shr[3];
  float k110[3];
  #pragma unroll
  for (int a=0;a<3;++a) k110[a] = cg.c110[a][0]*sh1 + cg.c110[a][1]*sh2 + cg.c110[a][2]*sh3;
  const float4* hr = reinterpret_cast<const float4*>(h + (size_t)s*32);
  float xs[32];
  #pragma unroll
  for (int i=0;i<8;++i){
    float4 q = hr[i];
    xs[i*4] = q.x; xs[i*4+1] = q.y; xs[i*4+2] = q.z; xs[i*4+3] = q.w;
  }
  float* ag = agg + (size_t)d*8;
  #pragma unroll
  for (int c=0;c<8;++c){
    float r = cg.c000*sh0*xs[c]*lw[c]
            + (k110[0]*xs[8+c] + k110[1]*xs[16+c] + k110[2]*xs[24+c])*lw[8+c];
    unsafeAtomicAdd(ag+c, r*w);
  }
}

__global__ __launch_bounds__(256) void node_fb_kernel(
    const float* __restrict__ agg, const float* __restrict__ si,
    float* __restrict__ out)
{
  __shared__ float s_si[128];
  if (threadIdx.x < 128) s_si[threadIdx.x] = si[threadIdx.x];
  __syncthreads();
  int idx = blockIdx.x*256 + threadIdx.x;
  if (idx >= NN*8) return;
  int n = idx >> 3, d = idx & 7;
  const float* ar = agg + (size_t)n*32;
  float y[4];
  #pragma unroll
  for (int m=0;m<4;++m){
    const float* sm = s_si + (m ? 64 : 0);
    float acc = 0.0f;
    #pragma unroll
    for (int c=0;c<8;++c) acc += ar[m*8+c]*sm[c*8+d];
    y[m] = acc;
  }
  float n0 = sqrtf(y[0]*y[0] + 1e-12f);
  float r0 = y[0]*(sspf(n0)/n0);
  float n1 = sqrtf(y[1]*y[1] + y[2]*y[2] + y[3]*y[3] + 1e-12f);
  float sc = sspf(n1)/n1;
  float* orow = out + (size_t)n*32;
  orow[d]      = r0;
  orow[8+d]    = y[1]*sc;
  orow[16+d]   = y[2]*sc;
  orow[24+d]   = y[3]*sc;
}

__global__ __launch_bounds__(256) void node3_fb_kernel(
    const float* __restrict__ agg, const float* __restrict__ si,
    const int* __restrict__ batch, float* __restrict__ g)
{
  __shared__ float s_si[64];
  if (threadIdx.x < 64) s_si[threadIdx.x] = si[threadIdx.x];
  __syncthreads();
  int n = blockIdx.x*256 + threadIdx.x;
  if (n >= NN) return;
  const float* ar = agg + (size_t)n*8;
  float av[8];
  #pragma unroll
  for (int c=0;c<8;++c) av[c] = ar[c];
  int b = batch[n];
  float* gr = g + (size_t)b*8;
  #pragma unroll
  for (int d=0;d<8;++d){
    float acc = 0.0f;
    #pragma unroll
    for (int c=0;c<8;++c) acc += av[c]*s_si[c*8+d];
    float v = acc / (1.0f + expf(-acc));
    unsafeAtomicAdd(gr+d, v);
  }
}

// ================= launch =================
extern "C" void kernel_launch(void* const* d_in, const int* in_sizes, int n_in,
                              void* d_out, int out_size, void* d_ws, size_t ws_size,
                              hipStream_t stream)
{
  const float* x     = (const float*)d_in[0];
  const int*   eidx  = (const int*)  d_in[1];
  const float* esh   = (const float*)d_in[2];
  const float* elen  = (const float*)d_in[3];
  const int*   batch = (const int*)  d_in[4];
  const float* wp1w  = (const float*)d_in[5];
  const float* wp1b  = (const float*)d_in[6];
  const float* wp2w  = (const float*)d_in[7];
  const float* wp2b  = (const float*)d_in[8];
  const float* wp3w  = (const float*)d_in[9];
  const float* wp3b  = (const float*)d_in[10];
  const float* si1   = (const float*)d_in[11];
  const float* si2   = (const float*)d_in[12];
  const float* si3   = (const float*)d_in[13];
  const float* outw  = (const float*)d_in[14];
  const float* outb  = (const float*)d_in[15];
  const int* src = eidx;
  const int* dst = eidx + NE;

  CGTables cg;
  build_cg_tables(cg);
  CGConsts K;
  build_cg_consts(cg, K);

  char* p = (char*)d_ws;
  auto carve = [&](size_t bytes) -> void* {
    void* r = (void*)p;
    p += ((bytes + 255)/256)*256;
    return r;
  };
  int*    rowptr = (int*)   carve((NN+1)*4);
  int*    perm   = (int*)   carve(NN*4);
  int*    bcnt   = (int*)   carve((NBUCK+1)*4);
  int*    bbase  = (int*)   carve((NBUCK+1)*4);
  int*    bclaim = (int*)   carve((NBUCK+1)*4);
  int*    dcnt   = (int*)   carve(256*4);
  int*    dcur   = (int*)   carve(256*4);
  float*  tab1   = (float*) carve(TBINS*16*4);
  float*  tab2   = (float*) carve(TB2*48*4);
  float*  tab3   = (float*) carve(TBINS*16*4);
  float*  G      = (float*) carve(512*4);
  float4* bufX   = (float4*)carve((size_t)NE*32);   // scatter dest; later aliased by B1/B2
  float4* bufY   = (float4*)carve((size_t)NE*32);   // sorted records (gather input)
  size_t need = (size_t)(p - (char*)d_ws);
  float* B1 = (float*)bufX;                          // 12.8MB, bufX dead after sortcopy
  float* B2 = (float*)bufX + (size_t)NN*32;          // next 12.8MB

  if (ws_size >= need){
    hipMemsetAsync(bcnt, 0, (NBUCK+1)*sizeof(int), stream);
    hipMemsetAsync(dcnt, 0, 256*sizeof(int), stream);
    hipMemsetAsync(G, 0, 512*sizeof(float), stream);
    lwtab_kernel<<<(TBINS*16+255)/256, 256, 0, stream>>>(wp1w, wp1b, 2, TBINS, tab1);
    lwtab_kernel<<<(TB2*48+255)/256, 256, 0, stream>>>(wp2w, wp2b, 6, TB2, tab2);
    lwtab_kernel<<<(TBINS*16+255)/256, 256, 0, stream>>>(wp3w, wp3b, 2, TBINS, tab3);
    bhist_kernel<<<SCB, 1024, 0, stream>>>(dst, bcnt);
    bscan_kernel<<<1, 1024, 0, stream>>>(bcnt, bbase, bclaim);
    scatter_rec_kernel<<<SCB, 1024, 0, stream>>>(src, dst, esh, elen, x, bclaim, bufX, K);
    sortcopy_kernel<<<NBUCK, 512, 0, stream>>>(bufX, bbase, bufY, rowptr);
    deg_hist_kernel<<<NBLK_SCAN, 256, 0, stream>>>(rowptr, dcnt);
    deg_scan_kernel<<<1, 256, 0, stream>>>(dcnt, dcur);
    deg_scatter_kernel<<<NBLK_SCAN, 256, 0, stream>>>(rowptr, dcur, perm);
    gather1_kernel<<<NBLK_N8, 256, 0, stream>>>(rowptr, perm, bufY, tab1, si1, B1, K);
    gather2_kernel<<<NBLK_N8, 256, 0, stream>>>(B1, rowptr, perm, bufY, tab2, si2, B2, K);
    gather3_kernel<<<NBLK_N8, 256, 0, stream>>>(B2, rowptr, perm, bufY, tab3, si3, batch, G, K);
    final_kernel<<<1, 64, 0, stream>>>(G, outw, outb, (float*)d_out);
  } else {
    // fallback: round-1 atomic path (~29 MB)
    float* A  = (float*)d_ws;
    float* Bf = A + (size_t)NN*32;
    float* Cf = Bf + (size_t)NN*32;
    float* Gf = Cf + (size_t)NN*8;
    hipMemsetAsync(A, 0, (size_t)NN*32*sizeof(float), stream);
    edge1_kernel<<<NBLK_E, 256, 0, stream>>>(x, src, dst, esh, elen, wp1w, wp1b, A, cg);
    node_fb_kernel<<<(NN*8+255)/256, 256, 0, stream>>>(A, si1, Bf);
    hipMemsetAsync(A, 0, (size_t)NN*32*sizeof(float), stream);
    edge2_kernel<<<NBLK_E, 256, 0, stream>>>(Bf, src, dst, esh, elen, wp2w, wp2b, A, cg);
    node_fb_kernel<<<(NN*8+255)/256, 256, 0, stream>>>(A, si2, Bf);
    hipMemsetAsync(Cf, 0, (size_t)NN*8*sizeof(float), stream);
    edge3_kernel<<<NBLK_E, 256, 0, stream>>>(Bf, src, dst, esh, elen, wp3w, wp3b, Cf, cg);
    hipMemsetAsync(Gf, 0, (size_t)NG*8*sizeof(float), stream);
    node3_fb_kernel<<<(NN+255)/256, 256, 0, stream>>>(Cf, si3, batch, Gf);
    final_kernel<<<1, 64, 0, stream>>>(Gf, outw, outb, (float*)d_out);
  }
}